// Round 6
// baseline (242.118 us; speedup 1.0000x reference)
//
#include <hip/hip_runtime.h>

// Izhikevich neuron scan. x: [B=16, C=64, N=1024, T=32] f32, T contiguous.
// 1M neurons = 16384 tiles of (64 neurons x 32 timesteps) = 8 KB tiles.
//
// R5 post-mortem: VGPR-staged "prefetch" can never pipeline — first use of
// a loaded register forces a full vmcnt drain before compute; sched_barrier
// didn't stop the sinking (VGPR stayed 44). R2-R5 all ~80us / 2.5 TB/s with
// VMEM idle during compute. fillBuffer: 6.7 TB/s on the same buffers.
//
// R6: async DMA staging. __builtin_amdgcn_global_load_lds(..,16,..) has no
// register result; the data dependency moves to the ds_read of the
// destination buffer one pipeline stage later. Two wave-private LDS buffers:
// process B_cur (ds_read -> recurrence -> spike transpose -> store) while 8
// DMA ops fill B_nxt. Single-wave blocks: NO barriers, so no barrier-drain.
//
// DMA dest is wave-uniform+lane*16 (no scatter, m104), so the XOR bank
// swizzle is applied to the GLOBAL lane mapping instead: instr k, lane L
// fetches float4 (k*64 + oct*8 + (grp^oct)) — bijection within each 128 B
// neuron row => still perfectly coalesced — landing so that chunk q of
// neuron n sits at slot q^(n&7). Every LDS phase is then 2 lanes/bank
// (free, m136) with static register indexing.
//
// Numerics: bit-exact f32 replication of the numpy reference (contract off,
// left-assoc order, literal spike-blend). LDS round-trip preserves bits.

#define TPB 64
#define ITERS 4

__device__ __forceinline__ void gl2lds16(const float* g, float* l) {
    __builtin_amdgcn_global_load_lds(
        (const __attribute__((address_space(1))) void*)g,
        (__attribute__((address_space(3))) void*)l, 16, 0, 0);
}

__global__ __launch_bounds__(TPB) void izhikevich_kernel(
    const float* __restrict__ x,
    const float* __restrict__ pa,
    const float* __restrict__ pb,
    const float* __restrict__ pc,
    const float* __restrict__ pd,
    float* __restrict__ out,
    int stride_tiles)
{
#pragma clang fp contract(off)
    __shared__ float B0[2048];   // 8 KB tile buffer (ping)
    __shared__ float B1[2048];   // 8 KB tile buffer (pong)

    const int lane = threadIdx.x;          // single-wave block
    const int oct  = lane >> 3;            // 0..7
    const int grp  = lane & 7;             // 0..7
    const int wid  = blockIdx.x;

    const float a = pa[0];
    const float b = pb[0];
    const float c = pc[0];
    const float d = pd[0];

    // Swizzled per-lane float4 index within each 64-float4 instruction group.
    const int lane_f4 = oct * 8 + (grp ^ oct);

    const float4* __restrict__ xin = reinterpret_cast<const float4*>(x);
    float4* __restrict__ op = reinterpret_cast<float4*>(out);

#define PREFETCH(tile, B)                                                     \
    do {                                                                      \
        const float* g =                                                      \
            x + (size_t)(tile) * 2048 + (size_t)lane_f4 * 4;                  \
        _Pragma("unroll")                                                     \
        for (int k = 0; k < 8; ++k) gl2lds16(g + k * 256, &(B)[k * 256]);     \
    } while (0)

    // Prologue: DMA tile 0 into B0.
    PREFETCH(wid, B0);

#pragma unroll
    for (int i = 0; i < ITERS; ++i) {
        float* __restrict__ cur = (i & 1) ? B1 : B0;   // compile-time select
        float* __restrict__ nxt = (i & 1) ? B0 : B1;
        const int tile = wid + i * stride_tiles;

        // ---- issue next tile's DMA (no register results; stays in flight
        //      across the entire processing phase below) -------------------
        if (i + 1 < ITERS) PREFETCH(tile + stride_tiles, nxt);
        __builtin_amdgcn_sched_barrier(0);

        // ---- read own neuron row (chunk q at slot q^grp; 2-way = free) ---
        float4 xs[8];
#pragma unroll
        for (int q = 0; q < 8; ++q)
            xs[q] = *reinterpret_cast<const float4*>(
                &cur[lane * 32 + ((q ^ grp) << 2)]);
        const float* xf = reinterpret_cast<const float*>(xs);

        // ---- recurrence, bit-exact ---------------------------------------
        float4 sp[8];
        float* sf = reinterpret_cast<float*>(sp);
        float v = 0.0f;
        float u = 0.0f;
#pragma unroll
        for (int j = 0; j < 32; ++j) {
            const float xt = xf[j];
            // dv = 0.04*v*v + 5.0*v + 140.0 - u + x_t   (left-assoc, no fma)
            const float t1 = (0.04f * v) * v;
            const float t2 = 5.0f * v;
            const float dv = (((t1 + t2) + 140.0f) - u) + xt;
            v = v + dv;                          // DT = 1.0 exact
            const float du = a * ((b * v) - u);
            u = u + du;
            const float spike = (v >= 30.0f) ? 1.0f : 0.0f;
            const float oms = 1.0f - spike;
            v = (v * oms) + (c * spike);         // exact for spike in {0,1}
            u = u + (d * spike);
            sf[j] = spike;
        }

        // ---- spikes back into own row (same swizzle; 2-way = free) -------
#pragma unroll
        for (int q = 0; q < 8; ++q)
            *reinterpret_cast<float4*>(&cur[lane * 32 + ((q ^ grp) << 2)]) =
                sp[q];

        // ---- straight readback + coalesced swizzled stores ---------------
        // LDS slot (k, lane) holds the spike float4 for global index
        // tile*512 + k*64 + lane_f4 (inverse of the DMA mapping).
#pragma unroll
        for (int k = 0; k < 8; ++k) {
            const float4 o = *reinterpret_cast<const float4*>(
                &cur[k * 256 + lane * 4]);
            op[(size_t)tile * 512 + k * 64 + lane_f4] = o;
        }
    }
#undef PREFETCH
}

extern "C" void kernel_launch(void* const* d_in, const int* in_sizes, int n_in,
                              void* d_out, int out_size, void* d_ws, size_t ws_size,
                              hipStream_t stream) {
    const float* x  = (const float*)d_in[0];
    const float* pa = (const float*)d_in[1];
    const float* pb = (const float*)d_in[2];
    const float* pc = (const float*)d_in[3];
    const float* pd = (const float*)d_in[4];
    float* out = (float*)d_out;

    const int n_neurons = in_sizes[0] / 32;        // 1,048,576
    const int n_tiles = n_neurons / 64;            // 16384
    const int grid = n_tiles / ITERS;              // 4096
    const int stride_tiles = grid;                 // grid-stride in tiles

    izhikevich_kernel<<<grid, TPB, 0, stream>>>(x, pa, pb, pc, pd, out,
                                                stride_tiles);
}